// Round 1
// baseline (98.681 us; speedup 1.0000x reference)
//
#include <hip/hip_runtime.h>

// DCT2D_Layer: 8x8 block DCT-II (norm=None) + zigzag reorder.
// img [16,3,512,512] f32 -> out [16, 3*64, 64, 64] f32
// One thread per 8x8 block. Lane order == bj -> coalesced 256B stores per k.

// Inverse zigzag: raster position p=u*8+v -> output channel index k.
__device__ __constant__ int INVZZ[64] = {
     0,  1,  5,  6, 14, 15, 27, 28,
     2,  4,  7, 13, 16, 26, 29, 42,
     3,  8, 12, 17, 25, 30, 41, 43,
     9, 11, 18, 24, 31, 40, 44, 53,
    10, 19, 23, 32, 39, 45, 52, 54,
    20, 22, 33, 38, 46, 51, 55, 60,
    21, 34, 37, 47, 50, 56, 59, 61,
    35, 36, 48, 49, 57, 58, 62, 63
};

__global__ __launch_bounds__(256) void dct2d_zigzag_kernel(
    const float* __restrict__ img, float* __restrict__ out)
{
    // 2*cos(m*pi/16)
    constexpr float c1 = 1.9615705608064609f;
    constexpr float c2 = 1.8477590650225735f;
    constexpr float c3 = 1.6629392246050905f;
    constexpr float c4 = 1.4142135623730951f;
    constexpr float c5 = 1.1111404660392044f;
    constexpr float c6 = 0.7653668647301796f;
    constexpr float c7 = 0.3901806440322565f;
    // C[k][x] = 2*cos(pi*(2x+1)*k/16)  (DCT-II basis, norm=None)
    const float C[8][8] = {
        { 2.f,  2.f,  2.f,  2.f,  2.f,  2.f,  2.f,  2.f},
        { c1,   c3,   c5,   c7,  -c7,  -c5,  -c3,  -c1},
        { c2,   c6,  -c6,  -c2,  -c2,  -c6,   c6,   c2},
        { c3,  -c7,  -c1,  -c5,   c5,   c1,   c7,  -c3},
        { c4,  -c4,  -c4,   c4,   c4,  -c4,  -c4,   c4},
        { c5,  -c1,   c7,   c3,  -c3,  -c7,   c1,  -c5},
        { c6,  -c2,   c2,  -c6,  -c6,   c2,  -c2,   c6},
        { c7,  -c5,   c3,  -c1,   c1,  -c3,   c5,  -c7},
    };

    const int tid = blockIdx.x * 256 + threadIdx.x;   // 0 .. 196607
    const int bj = tid & 63;          // block col (== lane within wave group)
    const int bi = (tid >> 6) & 63;   // block row
    const int bc = tid >> 12;         // b*3 + ch, 0..47

    // Input: img[bc, bi*8 + r, bj*8 + x], channel plane = 512*512 = 262144
    const float* __restrict__ src =
        img + (size_t)bc * 262144 + (size_t)bi * 8 * 512 + (size_t)bj * 8;

    float X[8][8];
#pragma unroll
    for (int r = 0; r < 8; ++r) {
        const float4 lo = *reinterpret_cast<const float4*>(src + r * 512);
        const float4 hi = *reinterpret_cast<const float4*>(src + r * 512 + 4);
        X[r][0] = lo.x; X[r][1] = lo.y; X[r][2] = lo.z; X[r][3] = lo.w;
        X[r][4] = hi.x; X[r][5] = hi.y; X[r][6] = hi.z; X[r][7] = hi.w;
    }

    // Output: out[bc*64 + k, bi, bj] over a 64x64 map -> base + k*4096
    float* __restrict__ dst =
        out + (size_t)bc * 262144 + (size_t)bi * 64 + (size_t)bj;

    // Z = C * X * C^T, with zigzag scatter on store.
#pragma unroll
    for (int u = 0; u < 8; ++u) {
        float t[8];
#pragma unroll
        for (int x = 0; x < 8; ++x) {
            float s = C[u][0] * X[0][x];
#pragma unroll
            for (int y = 1; y < 8; ++y) s += C[u][y] * X[y][x];
            t[x] = s;
        }
#pragma unroll
        for (int v = 0; v < 8; ++v) {
            float s = t[0] * C[v][0];
#pragma unroll
            for (int x = 1; x < 8; ++x) s += t[x] * C[v][x];
            dst[(size_t)INVZZ[u * 8 + v] * 4096] = s;
        }
    }
}

extern "C" void kernel_launch(void* const* d_in, const int* in_sizes, int n_in,
                              void* d_out, int out_size, void* d_ws, size_t ws_size,
                              hipStream_t stream)
{
    const float* img = (const float*)d_in[0];
    float* out = (float*)d_out;
    // total blocks = 16*3*64*64 = 196608 threads; 256/block -> 768 workgroups
    dct2d_zigzag_kernel<<<768, 256, 0, stream>>>(img, out);
}

// Round 2
// 96.262 us; speedup vs baseline: 1.0251x; 1.0251x over previous
//
#include <hip/hip_runtime.h>

// DCT2D_Layer: 8x8 block DCT-II (norm=None) + zigzag reorder.
// img [16,3,512,512] f32 -> out [16, 3*64, 64, 64] f32
// One thread per 8x8 block; lane == bj -> every wave store is 256B contiguous.
// v2: fully scalarized straight-line code (no local arrays -> no scratch),
//     factorized even/odd 8-pt DCT-II (~38 ops vs 64 FMA per transform),
//     zigzag plane offsets as literal constants per store.

// 2*cos(m*pi/16)
#define K1 1.9615705608064609f
#define K2 1.8477590650225735f
#define K3 1.6629392246050905f
#define K4 1.4142135623730951f
#define K5 1.1111404660392044f
#define K6 0.7653668647301796f
#define K7 0.3901806440322565f

// Unnormalized DCT-II, factor 2: y[k] = 2*sum_n x[n] cos(pi*(2n+1)k/16)
#define DCT8(x0,x1,x2,x3,x4,x5,x6,x7, y0,y1,y2,y3,y4,y5,y6,y7) do {        \
    float s0=(x0)+(x7), s1=(x1)+(x6), s2=(x2)+(x5), s3=(x3)+(x4);          \
    float d0=(x0)-(x7), d1=(x1)-(x6), d2=(x2)-(x5), d3=(x3)-(x4);          \
    float e0=s0+s3, e1=s1+s2, o0=s0-s3, o1=s1-s2;                          \
    y0 = 2.0f*(e0+e1);                                                     \
    y4 = K4*(e0-e1);                                                       \
    y2 = K2*o0 + K6*o1;                                                    \
    y6 = K6*o0 - K2*o1;                                                    \
    y1 = K1*d0 + K3*d1 + K5*d2 + K7*d3;                                    \
    y3 = K3*d0 - K7*d1 - K1*d2 - K5*d3;                                    \
    y5 = K5*d0 - K1*d1 + K7*d2 + K3*d3;                                    \
    y7 = K7*d0 - K5*d1 + K3*d2 - K1*d3;                                    \
} while (0)

// Row pass: load row r (two float4), transform, results into t{r}0..t{r}7.
#define ROWDCT(r) do {                                                     \
    const float4 lo = *reinterpret_cast<const float4*>(src + (r)*512);     \
    const float4 hi = *reinterpret_cast<const float4*>(src + (r)*512 + 4); \
    DCT8(lo.x,lo.y,lo.z,lo.w,hi.x,hi.y,hi.z,hi.w,                          \
         t##r##0,t##r##1,t##r##2,t##r##3,t##r##4,t##r##5,t##r##6,t##r##7); \
} while (0)

// Column pass for column v: transform t0v..t7v, store 8 results at the
// zigzag plane indices p0..p7 (literal constants; plane stride 64*64=4096).
#define COLSTORE(v, p0,p1,p2,p3,p4,p5,p6,p7) do {                          \
    float z0,z1,z2,z3,z4,z5,z6,z7;                                         \
    DCT8(t0##v,t1##v,t2##v,t3##v,t4##v,t5##v,t6##v,t7##v,                  \
         z0,z1,z2,z3,z4,z5,z6,z7);                                         \
    dst[(size_t)(p0)*4096] = z0;  dst[(size_t)(p1)*4096] = z1;             \
    dst[(size_t)(p2)*4096] = z2;  dst[(size_t)(p3)*4096] = z3;             \
    dst[(size_t)(p4)*4096] = z4;  dst[(size_t)(p5)*4096] = z5;             \
    dst[(size_t)(p6)*4096] = z6;  dst[(size_t)(p7)*4096] = z7;             \
} while (0)

__global__ __launch_bounds__(256) void dct2d_zigzag_kernel(
    const float* __restrict__ img, float* __restrict__ out)
{
    const int tid = blockIdx.x * 256 + threadIdx.x;   // 0 .. 196607
    const int bj = tid & 63;          // block col (== lane within wave)
    const int bi = (tid >> 6) & 63;   // block row
    const int bc = tid >> 12;         // b*3 + ch, 0..47

    // Input: img[bc, bi*8 + r, bj*8 + x]; channel plane = 512*512 = 262144
    const float* __restrict__ src =
        img + (size_t)bc * 262144 + (size_t)bi * 4096 + (size_t)bj * 8;

    // Output: out[bc*64 + k, bi, bj]; plane = 64*64 = 4096
    float* __restrict__ dst =
        out + (size_t)bc * 262144 + (size_t)bi * 64 + (size_t)bj;

    float t00,t01,t02,t03,t04,t05,t06,t07;
    float t10,t11,t12,t13,t14,t15,t16,t17;
    float t20,t21,t22,t23,t24,t25,t26,t27;
    float t30,t31,t32,t33,t34,t35,t36,t37;
    float t40,t41,t42,t43,t44,t45,t46,t47;
    float t50,t51,t52,t53,t54,t55,t56,t57;
    float t60,t61,t62,t63,t64,t65,t66,t67;
    float t70,t71,t72,t73,t74,t75,t76,t77;

    ROWDCT(0); ROWDCT(1); ROWDCT(2); ROWDCT(3);
    ROWDCT(4); ROWDCT(5); ROWDCT(6); ROWDCT(7);

    // Zigzag plane indices per (u,v): INVZZ[u*8+v] written as literals.
    COLSTORE(0,  0,  2,  3,  9, 10, 20, 21, 35);
    COLSTORE(1,  1,  4,  8, 11, 19, 22, 34, 36);
    COLSTORE(2,  5,  7, 12, 18, 23, 33, 37, 48);
    COLSTORE(3,  6, 13, 17, 24, 32, 38, 47, 49);
    COLSTORE(4, 14, 16, 25, 31, 39, 46, 50, 57);
    COLSTORE(5, 15, 26, 30, 40, 45, 51, 56, 58);
    COLSTORE(6, 27, 29, 41, 44, 52, 55, 59, 62);
    COLSTORE(7, 28, 42, 43, 53, 54, 60, 61, 63);
}

extern "C" void kernel_launch(void* const* d_in, const int* in_sizes, int n_in,
                              void* d_out, int out_size, void* d_ws, size_t ws_size,
                              hipStream_t stream)
{
    const float* img = (const float*)d_in[0];
    float* out = (float*)d_out;
    // 16*3*64*64 = 196608 threads; 256/block -> 768 workgroups
    dct2d_zigzag_kernel<<<768, 256, 0, stream>>>(img, out);
}